// Round 2
// baseline (3389.343 us; speedup 1.0000x reference)
//
#include <hip/hip_runtime.h>
#include <hip/hip_bf16.h>

typedef __attribute__((ext_vector_type(8))) short short8;   // 8 bf16 (4 VGPRs)
typedef __attribute__((ext_vector_type(4))) float f32x4;    // 4 f32 acc

#define K_DIM 1024
#define KT_N  32          // K_DIM / 32
#define M_TOK 2048
#define V_DIM 128000
#define BN    64

// softcap s = 30*tanh(l/30);  exp(s-30) = exp2(C2/(t+1)) with t = exp2(l*C1)
// C1 = 2*log2(e)/30, C2 = -60*log2(e)
#define CAP_C1 0.09617966939259757f
#define CAP_C2 -86.56170245333781f

static __device__ __forceinline__ short f2bf(float f) {
    unsigned u = __float_as_uint(f);
    u += 0x7FFFu + ((u >> 16) & 1u);      // RNE
    return (short)(u >> 16);
}

// ---------------- x (f32, row-major [2048][1024]) -> bf16 MFMA A-fragment layout ----------------
// frag index = (mt*KT_N + kt); within frag: lane holds A[mt*16 + (lane&15)][kt*32 + (lane>>4)*8 + e]
__global__ __launch_bounds__(256) void convert_x_kernel(const float* __restrict__ x,
                                                        short8* __restrict__ xf) {
    int o = blockIdx.x * 256 + threadIdx.x;       // 262144 short8 chunks total
    int lane = o & 63;
    int frag = o >> 6;
    int kt = frag & (KT_N - 1);
    int mt = frag >> 5;                           // frag / KT_N
    int row = (mt << 4) | (lane & 15);
    int k   = (kt << 5) | ((lane >> 4) << 3);
    const float4* s = (const float4*)(x + (size_t)row * K_DIM + k);
    float4 f0 = s[0], f1 = s[1];
    short8 b;
    b[0] = f2bf(f0.x); b[1] = f2bf(f0.y); b[2] = f2bf(f0.z); b[3] = f2bf(f0.w);
    b[4] = f2bf(f1.x); b[5] = f2bf(f1.y); b[6] = f2bf(f1.z); b[7] = f2bf(f1.w);
    xf[o] = b;
}

// ---------------- persistent-vocab sum-exp GEMM ----------------
// One block per 64 vocab rows. W slice staged once f32->bf16 into LDS (fragment
// layout, 128 KiB), then 8 waves (4 m-rows x 2 n-cols) sweep all 2048 tokens.
__global__ __launch_bounds__(512) void sumexp_kernel(const float* __restrict__ W,
                                                     const short8* __restrict__ xf,
                                                     float* __restrict__ rowsum) {
    __shared__ short8 Bl[4 * KT_N * 64];          // [nt(4)][kt(32)][lane(64)] = 128 KiB
    const int tid = threadIdx.x;
    const size_t v0 = (size_t)blockIdx.x * BN;

    // stage + convert: 64 rows x 1024 cols, 8 elems/thread/iter
    #pragma unroll
    for (int i = 0; i < 16; ++i) {
        int c   = tid + (i << 9);                 // 0..8191
        int row = c >> 7;                         // 128 chunks per row
        int k8  = c & 127;
        const float4* src = (const float4*)(W + (v0 + row) * K_DIM + (k8 << 3));
        float4 f0 = src[0], f1 = src[1];
        short8 b;
        b[0] = f2bf(f0.x); b[1] = f2bf(f0.y); b[2] = f2bf(f0.z); b[3] = f2bf(f0.w);
        b[4] = f2bf(f1.x); b[5] = f2bf(f1.y); b[6] = f2bf(f1.z); b[7] = f2bf(f1.w);
        int kt    = k8 >> 2;
        int lane2 = (row & 15) | ((k8 & 3) << 4);
        int nt    = row >> 4;
        Bl[(((nt << 5) | kt) << 6) + lane2] = b;
    }
    __syncthreads();

    const int wid  = tid >> 6;
    const int lane = tid & 63;
    const int wr   = wid >> 1;                    // 0..3  (m)
    const int wc   = wid & 1;                     // 0..1  (n)

    for (int ch = 0; ch < 8; ++ch) {              // 8 chunks of 256 tokens
        const int mt_base = (ch << 4) + (wr << 2);
        f32x4 acc[4][2] = {};
        for (int kt = 0; kt < KT_N; ++kt) {
            short8 a0 = xf[((mt_base + 0) * KT_N + kt) * 64 + lane];
            short8 a1 = xf[((mt_base + 1) * KT_N + kt) * 64 + lane];
            short8 a2 = xf[((mt_base + 2) * KT_N + kt) * 64 + lane];
            short8 a3 = xf[((mt_base + 3) * KT_N + kt) * 64 + lane];
            short8 b0 = Bl[((((wc << 1) | 0) * KT_N + kt) << 6) + lane];
            short8 b1 = Bl[((((wc << 1) | 1) * KT_N + kt) << 6) + lane];
            acc[0][0] = __builtin_amdgcn_mfma_f32_16x16x32_bf16(a0, b0, acc[0][0], 0, 0, 0);
            acc[0][1] = __builtin_amdgcn_mfma_f32_16x16x32_bf16(a0, b1, acc[0][1], 0, 0, 0);
            acc[1][0] = __builtin_amdgcn_mfma_f32_16x16x32_bf16(a1, b0, acc[1][0], 0, 0, 0);
            acc[1][1] = __builtin_amdgcn_mfma_f32_16x16x32_bf16(a1, b1, acc[1][1], 0, 0, 0);
            acc[2][0] = __builtin_amdgcn_mfma_f32_16x16x32_bf16(a2, b0, acc[2][0], 0, 0, 0);
            acc[2][1] = __builtin_amdgcn_mfma_f32_16x16x32_bf16(a2, b1, acc[2][1], 0, 0, 0);
            acc[3][0] = __builtin_amdgcn_mfma_f32_16x16x32_bf16(a3, b0, acc[3][0], 0, 0, 0);
            acc[3][1] = __builtin_amdgcn_mfma_f32_16x16x32_bf16(a3, b1, acc[3][1], 0, 0, 0);
        }
        // epilogue: softcap+exp, sum over this wave's 32 vocab cols, atomic into rowsum
        #pragma unroll
        for (int mf = 0; mf < 4; ++mf) {
            float e[4];
            #pragma unroll
            for (int r = 0; r < 4; ++r) {
                float l0 = acc[mf][0][r], l1 = acc[mf][1][r];
                float t0 = exp2f(l0 * CAP_C1), t1 = exp2f(l1 * CAP_C1);
                e[r] = exp2f(CAP_C2 / (t0 + 1.0f)) + exp2f(CAP_C2 / (t1 + 1.0f));
            }
            #pragma unroll
            for (int off = 1; off < 16; off <<= 1) {
                e[0] += __shfl_xor(e[0], off, 64);
                e[1] += __shfl_xor(e[1], off, 64);
                e[2] += __shfl_xor(e[2], off, 64);
                e[3] += __shfl_xor(e[3], off, 64);
            }
            if ((lane & 15) == 0) {
                int rowb = (ch << 8) + (wr << 6) + (mf << 4) + ((lane >> 4) << 2);
                atomicAdd(&rowsum[rowb + 0], e[0]);
                atomicAdd(&rowsum[rowb + 1], e[1]);
                atomicAdd(&rowsum[rowb + 2], e[2]);
                atomicAdd(&rowsum[rowb + 3], e[3]);
            }
        }
    }
}

// ---------------- exact-f32 label logits: one wave per token ----------------
__global__ __launch_bounds__(256) void label_kernel(const float* __restrict__ x,
                                                    const float* __restrict__ W,
                                                    const int* __restrict__ target,
                                                    float* __restrict__ slabel) {
    int t    = blockIdx.x * 4 + (threadIdx.x >> 6);
    int lane = threadIdx.x & 63;
    int tg   = target[t];
    int lbl  = (tg == -100) ? 0 : tg;
    const float4* xr = (const float4*)(x + (size_t)t * K_DIM);
    const float4* wv = (const float4*)(W + (size_t)lbl * K_DIM);
    float sum = 0.0f;
    #pragma unroll
    for (int i = 0; i < 4; ++i) {
        float4 a = xr[lane + i * 64];
        float4 b = wv[lane + i * 64];
        sum += a.x * b.x + a.y * b.y + a.z * b.z + a.w * b.w;
    }
    #pragma unroll
    for (int off = 1; off < 64; off <<= 1) sum += __shfl_xor(sum, off, 64);
    if (lane == 0) {
        float t0 = exp2f(sum * CAP_C1);
        slabel[t] = 30.0f - 60.0f / (t0 + 1.0f);   // 30*tanh(sum/30)
    }
}

// ---------------- finalize: per-row masked mean of logp, DPO-style scalar ----------------
__global__ __launch_bounds__(256) void finalize_kernel(const float* __restrict__ rowsum,
                                                       const float* __restrict__ slabel,
                                                       const int* __restrict__ target,
                                                       float* __restrict__ out) {
    __shared__ double ssum[4];
    __shared__ int    scnt[4];
    int w    = threadIdx.x >> 6;                  // wave -> batch row
    int lane = threadIdx.x & 63;
    double acc = 0.0;
    int cnt = 0;
    #pragma unroll
    for (int j = 0; j < 8; ++j) {
        int t = w * 512 + j * 64 + lane;
        int tg = target[t];
        if (tg != -100) {
            float lse = 30.0f + logf(rowsum[t]);
            acc += (double)(slabel[t] - lse);
            cnt += 1;
        }
    }
    #pragma unroll
    for (int off = 1; off < 64; off <<= 1) {
        acc += __shfl_xor(acc, off, 64);
        cnt += __shfl_xor(cnt, off, 64);
    }
    if (lane == 0) { ssum[w] = acc; scnt[w] = cnt; }
    __syncthreads();
    if (threadIdx.x == 0) {
        double c0 = ssum[0] / (double)scnt[0];
        double c1 = ssum[1] / (double)scnt[1];
        double r0 = ssum[2] / (double)scnt[2];
        double r1 = ssum[3] / (double)scnt[3];
        out[0] = (float)(-0.1 * 0.5 * ((c0 - r0) + (c1 - r1)));
    }
}

extern "C" void kernel_launch(void* const* d_in, const int* in_sizes, int n_in,
                              void* d_out, int out_size, void* d_ws, size_t ws_size,
                              hipStream_t stream) {
    const float* x      = (const float*)d_in[0];
    const float* W      = (const float*)d_in[1];
    const int*   target = (const int*)d_in[2];
    float*       out    = (float*)d_out;

    char*   ws     = (char*)d_ws;
    short8* xf     = (short8*)ws;                               // 4 MiB (2048*1024 bf16)
    float*  rowsum = (float*)(ws + (size_t)(4 << 20));          // 8 KiB
    float*  slabel = (float*)(ws + (size_t)(4 << 20) + 8192);   // 8 KiB

    hipMemsetAsync(rowsum, 0, M_TOK * sizeof(float), stream);
    convert_x_kernel<<<M_TOK * (K_DIM / 8) / 256, 256, 0, stream>>>(x, xf);
    sumexp_kernel<<<V_DIM / BN, 512, 0, stream>>>(W, xf, rowsum);
    label_kernel<<<M_TOK / 4, 256, 0, stream>>>(x, W, target, slabel);
    finalize_kernel<<<1, 256, 0, stream>>>(rowsum, slabel, target, out);
}

// Round 3
// 1154.110 us; speedup vs baseline: 2.9368x; 2.9368x over previous
//
#include <hip/hip_runtime.h>
#include <hip/hip_bf16.h>

typedef __attribute__((ext_vector_type(8))) short short8;   // 8 bf16 (4 VGPRs)
typedef __attribute__((ext_vector_type(4))) float f32x4;    // 4 f32 acc

#define K_DIM 1024
#define KT_N  32          // K_DIM / 32
#define M_TOK 2048
#define V_DIM 128000
#define NKSTEP 32         // K steps of BK=32

// softcap s = 30*tanh(l/30);  exp(s-30) = exp2(C2/(t+1)) with t = exp2(l*C1)
#define CAP_C1 0.09617966939259757f
#define CAP_C2 -86.56170245333781f

static __device__ __forceinline__ short f2bf(float f) {
    unsigned u = __float_as_uint(f);
    u += 0x7FFFu + ((u >> 16) & 1u);      // RNE
    return (short)(u >> 16);
}

static __device__ __forceinline__ short8 pack8(float4 a, float4 b) {
    short8 r;
    r[0] = f2bf(a.x); r[1] = f2bf(a.y); r[2] = f2bf(a.z); r[3] = f2bf(a.w);
    r[4] = f2bf(b.x); r[5] = f2bf(b.y); r[6] = f2bf(b.z); r[7] = f2bf(b.w);
    return r;
}

static __device__ __forceinline__ void gload16(const void* g, void* lds) {
    __builtin_amdgcn_global_load_lds(
        (const __attribute__((address_space(1))) unsigned int*)g,
        (__attribute__((address_space(3))) unsigned int*)lds, 16, 0, 0);
}

// ---------------- x (f32, row-major [2048][1024]) -> bf16 MFMA fragment layout ----------------
// frag index = (mt*KT_N + kt); lane holds x[mt*16 + (lane&15)][kt*32 + (lane>>4)*8 + e]
__global__ __launch_bounds__(256) void convert_x_kernel(const float* __restrict__ x,
                                                        short8* __restrict__ xf) {
    int o = blockIdx.x * 256 + threadIdx.x;
    int lane = o & 63;
    int frag = o >> 6;
    int kt = frag & (KT_N - 1);
    int mt = frag >> 5;
    int row = (mt << 4) | (lane & 15);
    int k   = (kt << 5) | ((lane >> 4) << 3);
    const float4* s = (const float4*)(x + (size_t)row * K_DIM + k);
    xf[o] = pack8(s[0], s[1]);
}

// ---------------- tiled GEMM + softcap-exp + vocab-reduce ----------------
// Tile 128 vocab x 128 tokens, BK=32. 4 waves (2x2), 64x64 out each.
// A (W f32) reg-staged->bf16->LDS frag layout; B (xf bf16) via global_load_lds.
// Double-buffered, 1 barrier/K-step, prefetch t+1 before MFMA on t.
__global__ __launch_bounds__(256, 3) void gemm_sumexp_kernel(const float* __restrict__ W,
                                                             const short8* __restrict__ xf,
                                                             float* __restrict__ rowsum) {
    __shared__ short8 As[2][512];        // [buf][frag(8)*64 + lane] = 8 KiB/buf
    __shared__ short8 Bs[2][512];

    // XCD-aware swizzle (16000 % 8 == 0 -> bijective): consecutive work ids share W panel
    int bid = blockIdx.x;
    int wk  = (bid & 7) * ((V_DIM / 128) * 16 / 8) + (bid >> 3);
    int vt  = wk >> 4;                   // vocab tile 0..999
    int tt  = wk & 15;                   // token tile 0..15

    const int tid  = threadIdx.x;
    const int lane = tid & 63;
    const int wid  = tid >> 6;
    const int wr   = (wid >> 1) & 1;     // wave row (vocab)
    const int wc   = wid & 1;            // wave col (tokens)

    // A staging map: thread -> (frag mt_s, slot sl); covers frag-lanes sl and sl+32
    const int mt_s = tid >> 5;           // 0..7
    const int sl   = tid & 31;
    const float* arow_p = W + (size_t)(vt * 128 + mt_s * 16 + (sl & 15)) * K_DIM
                            + ((sl >> 4) << 3);
    // B staging: wave wid issues frags {2*wid, 2*wid+1}
    const int nt0 = wid << 1;
    const char* gb_base = (const char*)xf
        + ((((size_t)(tt * 8 + nt0)) * KT_N) * 64 + lane) * 16;

    // ---- prologue: stage K-step 0 into buf 0 ----
    {
        const float4* ga = (const float4*)(arow_p + 0);
        float4 p0 = ga[0], p1 = ga[1], p2 = ga[4], p3 = ga[5];
        gload16(gb_base,             &Bs[0][nt0 * 64]);
        gload16(gb_base + 32768,     &Bs[0][(nt0 + 1) * 64]);   // +KT_N*64*16
        As[0][mt_s * 64 + sl]      = pack8(p0, p1);
        As[0][mt_s * 64 + sl + 32] = pack8(p2, p3);
    }
    __syncthreads();

    f32x4 acc[4][4] = {};
    int cur = 0;
    for (int t = 0; t < NKSTEP; ++t) {
        float4 q0, q1, q2, q3;
        if (t + 1 < NKSTEP) {
            const float4* ga = (const float4*)(arow_p + (t + 1) * 32);
            q0 = ga[0]; q1 = ga[1]; q2 = ga[4]; q3 = ga[5];
            gload16(gb_base + (size_t)(t + 1) * 1024,         &Bs[cur ^ 1][nt0 * 64]);
            gload16(gb_base + (size_t)(t + 1) * 1024 + 32768, &Bs[cur ^ 1][(nt0 + 1) * 64]);
        }
        short8 af0 = As[cur][(wr * 4 + 0) * 64 + lane];
        short8 af1 = As[cur][(wr * 4 + 1) * 64 + lane];
        short8 af2 = As[cur][(wr * 4 + 2) * 64 + lane];
        short8 af3 = As[cur][(wr * 4 + 3) * 64 + lane];
        short8 bf0 = Bs[cur][(wc * 4 + 0) * 64 + lane];
        short8 bf1 = Bs[cur][(wc * 4 + 1) * 64 + lane];
        short8 bf2 = Bs[cur][(wc * 4 + 2) * 64 + lane];
        short8 bf3 = Bs[cur][(wc * 4 + 3) * 64 + lane];
        acc[0][0] = __builtin_amdgcn_mfma_f32_16x16x32_bf16(af0, bf0, acc[0][0], 0, 0, 0);
        acc[0][1] = __builtin_amdgcn_mfma_f32_16x16x32_bf16(af0, bf1, acc[0][1], 0, 0, 0);
        acc[0][2] = __builtin_amdgcn_mfma_f32_16x16x32_bf16(af0, bf2, acc[0][2], 0, 0, 0);
        acc[0][3] = __builtin_amdgcn_mfma_f32_16x16x32_bf16(af0, bf3, acc[0][3], 0, 0, 0);
        acc[1][0] = __builtin_amdgcn_mfma_f32_16x16x32_bf16(af1, bf0, acc[1][0], 0, 0, 0);
        acc[1][1] = __builtin_amdgcn_mfma_f32_16x16x32_bf16(af1, bf1, acc[1][1], 0, 0, 0);
        acc[1][2] = __builtin_amdgcn_mfma_f32_16x16x32_bf16(af1, bf2, acc[1][2], 0, 0, 0);
        acc[1][3] = __builtin_amdgcn_mfma_f32_16x16x32_bf16(af1, bf3, acc[1][3], 0, 0, 0);
        acc[2][0] = __builtin_amdgcn_mfma_f32_16x16x32_bf16(af2, bf0, acc[2][0], 0, 0, 0);
        acc[2][1] = __builtin_amdgcn_mfma_f32_16x16x32_bf16(af2, bf1, acc[2][1], 0, 0, 0);
        acc[2][2] = __builtin_amdgcn_mfma_f32_16x16x32_bf16(af2, bf2, acc[2][2], 0, 0, 0);
        acc[2][3] = __builtin_amdgcn_mfma_f32_16x16x32_bf16(af2, bf3, acc[2][3], 0, 0, 0);
        acc[3][0] = __builtin_amdgcn_mfma_f32_16x16x32_bf16(af3, bf0, acc[3][0], 0, 0, 0);
        acc[3][1] = __builtin_amdgcn_mfma_f32_16x16x32_bf16(af3, bf1, acc[3][1], 0, 0, 0);
        acc[3][2] = __builtin_amdgcn_mfma_f32_16x16x32_bf16(af3, bf2, acc[3][2], 0, 0, 0);
        acc[3][3] = __builtin_amdgcn_mfma_f32_16x16x32_bf16(af3, bf3, acc[3][3], 0, 0, 0);
        if (t + 1 < NKSTEP) {
            As[cur ^ 1][mt_s * 64 + sl]      = pack8(q0, q1);
            As[cur ^ 1][mt_s * 64 + sl + 32] = pack8(q2, q3);
        }
        __syncthreads();
        cur ^= 1;
    }

    // ---- epilogue: softcap+exp, reduce over vocab (rows), atomics per token ----
    float s0 = 0.f, s1 = 0.f, s2 = 0.f, s3 = 0.f;
    #pragma unroll
    for (int mi = 0; mi < 4; ++mi) {
        #pragma unroll
        for (int r = 0; r < 4; ++r) {
            float l0 = acc[mi][0][r], l1 = acc[mi][1][r];
            float l2 = acc[mi][2][r], l3 = acc[mi][3][r];
            s0 += exp2f(CAP_C2 * __builtin_amdgcn_rcpf(exp2f(l0 * CAP_C1) + 1.0f));
            s1 += exp2f(CAP_C2 * __builtin_amdgcn_rcpf(exp2f(l1 * CAP_C1) + 1.0f));
            s2 += exp2f(CAP_C2 * __builtin_amdgcn_rcpf(exp2f(l2 * CAP_C1) + 1.0f));
            s3 += exp2f(CAP_C2 * __builtin_amdgcn_rcpf(exp2f(l3 * CAP_C1) + 1.0f));
        }
    }
    s0 += __shfl_xor(s0, 16, 64); s0 += __shfl_xor(s0, 32, 64);
    s1 += __shfl_xor(s1, 16, 64); s1 += __shfl_xor(s1, 32, 64);
    s2 += __shfl_xor(s2, 16, 64); s2 += __shfl_xor(s2, 32, 64);
    s3 += __shfl_xor(s3, 16, 64); s3 += __shfl_xor(s3, 32, 64);
    if (lane < 16) {
        int tbase = tt * 128 + wc * 64 + lane;
        atomicAdd(&rowsum[tbase +  0], s0);
        atomicAdd(&rowsum[tbase + 16], s1);
        atomicAdd(&rowsum[tbase + 32], s2);
        atomicAdd(&rowsum[tbase + 48], s3);
    }
}

// ---------------- exact-f32 label logits: one wave per token ----------------
__global__ __launch_bounds__(256) void label_kernel(const float* __restrict__ x,
                                                    const float* __restrict__ W,
                                                    const int* __restrict__ target,
                                                    float* __restrict__ slabel) {
    int t    = blockIdx.x * 4 + (threadIdx.x >> 6);
    int lane = threadIdx.x & 63;
    int tg   = target[t];
    int lbl  = (tg == -100) ? 0 : tg;
    const float4* xr = (const float4*)(x + (size_t)t * K_DIM);
    const float4* wv = (const float4*)(W + (size_t)lbl * K_DIM);
    float sum = 0.0f;
    #pragma unroll
    for (int i = 0; i < 4; ++i) {
        float4 a = xr[lane + i * 64];
        float4 b = wv[lane + i * 64];
        sum += a.x * b.x + a.y * b.y + a.z * b.z + a.w * b.w;
    }
    #pragma unroll
    for (int off = 1; off < 64; off <<= 1) sum += __shfl_xor(sum, off, 64);
    if (lane == 0) {
        float t0 = exp2f(sum * CAP_C1);
        slabel[t] = 30.0f - 60.0f / (t0 + 1.0f);   // 30*tanh(sum/30)
    }
}

// ---------------- finalize ----------------
__global__ __launch_bounds__(256) void finalize_kernel(const float* __restrict__ rowsum,
                                                       const float* __restrict__ slabel,
                                                       const int* __restrict__ target,
                                                       float* __restrict__ out) {
    __shared__ double ssum[4];
    __shared__ int    scnt[4];
    int w    = threadIdx.x >> 6;
    int lane = threadIdx.x & 63;
    double acc = 0.0;
    int cnt = 0;
    #pragma unroll
    for (int j = 0; j < 8; ++j) {
        int t = w * 512 + j * 64 + lane;
        int tg = target[t];
        if (tg != -100) {
            float lse = 30.0f + logf(rowsum[t]);
            acc += (double)(slabel[t] - lse);
            cnt += 1;
        }
    }
    #pragma unroll
    for (int off = 1; off < 64; off <<= 1) {
        acc += __shfl_xor(acc, off, 64);
        cnt += __shfl_xor(cnt, off, 64);
    }
    if (lane == 0) { ssum[w] = acc; scnt[w] = cnt; }
    __syncthreads();
    if (threadIdx.x == 0) {
        double c0 = ssum[0] / (double)scnt[0];
        double c1 = ssum[1] / (double)scnt[1];
        double r0 = ssum[2] / (double)scnt[2];
        double r1 = ssum[3] / (double)scnt[3];
        out[0] = (float)(-0.1 * 0.5 * ((c0 - r0) + (c1 - r1)));
    }
}

extern "C" void kernel_launch(void* const* d_in, const int* in_sizes, int n_in,
                              void* d_out, int out_size, void* d_ws, size_t ws_size,
                              hipStream_t stream) {
    const float* x      = (const float*)d_in[0];
    const float* W      = (const float*)d_in[1];
    const int*   target = (const int*)d_in[2];
    float*       out    = (float*)d_out;

    char*   ws     = (char*)d_ws;
    short8* xf     = (short8*)ws;                               // 4 MiB
    float*  rowsum = (float*)(ws + (size_t)(4 << 20));          // 8 KiB
    float*  slabel = (float*)(ws + (size_t)(4 << 20) + 8192);   // 8 KiB

    hipMemsetAsync(rowsum, 0, M_TOK * sizeof(float), stream);
    convert_x_kernel<<<M_TOK * (K_DIM / 8) / 256, 256, 0, stream>>>(x, xf);
    gemm_sumexp_kernel<<<(V_DIM / 128) * 16, 256, 0, stream>>>(W, xf, rowsum);
    label_kernel<<<M_TOK / 4, 256, 0, stream>>>(x, W, target, slabel);
    finalize_kernel<<<1, 256, 0, stream>>>(rowsum, slabel, target, out);
}

// Round 4
// 726.069 us; speedup vs baseline: 4.6681x; 1.5895x over previous
//
#include <hip/hip_runtime.h>
#include <hip/hip_bf16.h>

typedef __attribute__((ext_vector_type(8))) short short8;   // 8 bf16 (4 VGPRs)
typedef __attribute__((ext_vector_type(4))) float f32x4;    // 4 f32 acc

#define K_DIM 1024
#define KT_N  32          // K_DIM / 32
#define M_TOK 2048
#define V_DIM 128000
#define NKSTEP 32         // K steps of BK=32

// softcap s = 30*tanh(l/30);  exp(s-30) = exp2(C2/(t+1)) with t = exp2(l*C1)
#define CAP_C1 0.09617966939259757f
#define CAP_C2 -86.56170245333781f

// workspace layout (bytes)
#define WS_ROWSUM 0
#define WS_SLABEL 8192
#define WS_XF     16384
#define WS_WF     (16384 + (4u << 20))
#define WS_REQ    ((size_t)WS_WF + (size_t)V_DIM * K_DIM * 2)

static __device__ __forceinline__ short f2bf(float f) {
    unsigned u = __float_as_uint(f);
    u += 0x7FFFu + ((u >> 16) & 1u);      // RNE
    return (short)(u >> 16);
}

static __device__ __forceinline__ short8 pack8(float4 a, float4 b) {
    short8 r;
    r[0] = f2bf(a.x); r[1] = f2bf(a.y); r[2] = f2bf(a.z); r[3] = f2bf(a.w);
    r[4] = f2bf(b.x); r[5] = f2bf(b.y); r[6] = f2bf(b.z); r[7] = f2bf(b.w);
    return r;
}

static __device__ __forceinline__ void gload16(const void* g, void* lds) {
    __builtin_amdgcn_global_load_lds(
        (const __attribute__((address_space(1))) unsigned int*)g,
        (__attribute__((address_space(3))) unsigned int*)lds, 16, 0, 0);
}

// ---------------- f32 row-major -> bf16 MFMA fragment layout ----------------
// frag f = (mt*KT_N + kt); lane holds M[mt*16 + (lane&15)][kt*32 + (lane>>4)*8 + e]
__global__ __launch_bounds__(256) void convert_x_kernel(const float* __restrict__ x,
                                                        short8* __restrict__ xf) {
    int o = blockIdx.x * 256 + threadIdx.x;
    int lane = o & 63;
    int frag = o >> 6;
    int kt = frag & (KT_N - 1);
    int mt = frag >> 5;
    int row = (mt << 4) | (lane & 15);
    int k   = (kt << 5) | ((lane >> 4) << 3);
    const float4* s = (const float4*)(x + (size_t)row * K_DIM + k);
    xf[o] = pack8(s[0], s[1]);
}

__global__ __launch_bounds__(256) void convert_w_kernel(const float* __restrict__ W,
                                                        short8* __restrict__ wf) {
    int o = blockIdx.x * 256 + threadIdx.x;       // 16,384,000 chunks
    int lane = o & 63;
    int frag = o >> 6;
    int kt = frag & (KT_N - 1);
    int mt = frag >> 5;                           // 0..7999
    int row = (mt << 4) | (lane & 15);
    int k   = (kt << 5) | ((lane >> 4) << 3);
    const float4* s = (const float4*)(W + (size_t)row * K_DIM + k);
    wf[o] = pack8(s[0], s[1]);
}

// ---------------- main GEMM (m97 structure): both operands bf16 via global_load_lds ----------------
// Tile 128 vocab x 128 tokens, BK=32, 4 waves (2x2), 64x64 out/wave, dbuf LDS, 1 barrier/K-step.
__global__ __launch_bounds__(256, 3) void gemm_sumexp_bf16(const short8* __restrict__ wf,
                                                           const short8* __restrict__ xf,
                                                           float* __restrict__ rowsum) {
    __shared__ short8 As[2][512];        // 8 frags * 64 lanes, dbuf = 16 KiB
    __shared__ short8 Bs[2][512];

    // XCD swizzle (16000 % 8 == 0 -> bijective)
    int bid = blockIdx.x;
    int wk  = (bid & 7) * (16000 / 8) + (bid >> 3);
    int vt  = wk >> 4;                   // vocab tile 0..999
    int tt  = wk & 15;                   // token tile 0..15

    const int tid  = threadIdx.x;
    const int lane = tid & 63;
    const int wid  = tid >> 6;
    const int wr   = (wid >> 1) & 1;     // wave row (vocab)
    const int wc   = wid & 1;            // wave col (tokens)

    // staging: wave wid stages A-frags {2wid, 2wid+1} and B-frags {2wid, 2wid+1}
    const int f0 = wid << 1;
    const char* ga = (const char*)wf + (((size_t)(vt * 8 + f0) * KT_N) * 64 + lane) * 16;
    const char* gb = (const char*)xf + (((size_t)(tt * 8 + f0) * KT_N) * 64 + lane) * 16;
    // byte stride between mt and mt+1 at same kt: KT_N*64*16 = 32768; kt stride = 1024

    // prologue: K-step 0 -> buf 0
    gload16(ga,         &As[0][f0 * 64]);
    gload16(ga + 32768, &As[0][(f0 + 1) * 64]);
    gload16(gb,         &Bs[0][f0 * 64]);
    gload16(gb + 32768, &Bs[0][(f0 + 1) * 64]);
    __syncthreads();

    f32x4 acc[4][4] = {};
    int cur = 0;
    for (int t = 0; t < NKSTEP; ++t) {
        if (t + 1 < NKSTEP) {
            size_t off = (size_t)(t + 1) * 1024;
            gload16(ga + off,         &As[cur ^ 1][f0 * 64]);
            gload16(ga + off + 32768, &As[cur ^ 1][(f0 + 1) * 64]);
            gload16(gb + off,         &Bs[cur ^ 1][f0 * 64]);
            gload16(gb + off + 32768, &Bs[cur ^ 1][(f0 + 1) * 64]);
        }
        short8 af0 = As[cur][(wr * 4 + 0) * 64 + lane];
        short8 af1 = As[cur][(wr * 4 + 1) * 64 + lane];
        short8 af2 = As[cur][(wr * 4 + 2) * 64 + lane];
        short8 af3 = As[cur][(wr * 4 + 3) * 64 + lane];
        short8 bf0 = Bs[cur][(wc * 4 + 0) * 64 + lane];
        short8 bf1 = Bs[cur][(wc * 4 + 1) * 64 + lane];
        short8 bf2 = Bs[cur][(wc * 4 + 2) * 64 + lane];
        short8 bf3 = Bs[cur][(wc * 4 + 3) * 64 + lane];
        acc[0][0] = __builtin_amdgcn_mfma_f32_16x16x32_bf16(af0, bf0, acc[0][0], 0, 0, 0);
        acc[0][1] = __builtin_amdgcn_mfma_f32_16x16x32_bf16(af0, bf1, acc[0][1], 0, 0, 0);
        acc[0][2] = __builtin_amdgcn_mfma_f32_16x16x32_bf16(af0, bf2, acc[0][2], 0, 0, 0);
        acc[0][3] = __builtin_amdgcn_mfma_f32_16x16x32_bf16(af0, bf3, acc[0][3], 0, 0, 0);
        acc[1][0] = __builtin_amdgcn_mfma_f32_16x16x32_bf16(af1, bf0, acc[1][0], 0, 0, 0);
        acc[1][1] = __builtin_amdgcn_mfma_f32_16x16x32_bf16(af1, bf1, acc[1][1], 0, 0, 0);
        acc[1][2] = __builtin_amdgcn_mfma_f32_16x16x32_bf16(af1, bf2, acc[1][2], 0, 0, 0);
        acc[1][3] = __builtin_amdgcn_mfma_f32_16x16x32_bf16(af1, bf3, acc[1][3], 0, 0, 0);
        acc[2][0] = __builtin_amdgcn_mfma_f32_16x16x32_bf16(af2, bf0, acc[2][0], 0, 0, 0);
        acc[2][1] = __builtin_amdgcn_mfma_f32_16x16x32_bf16(af2, bf1, acc[2][1], 0, 0, 0);
        acc[2][2] = __builtin_amdgcn_mfma_f32_16x16x32_bf16(af2, bf2, acc[2][2], 0, 0, 0);
        acc[2][3] = __builtin_amdgcn_mfma_f32_16x16x32_bf16(af2, bf3, acc[2][3], 0, 0, 0);
        acc[3][0] = __builtin_amdgcn_mfma_f32_16x16x32_bf16(af3, bf0, acc[3][0], 0, 0, 0);
        acc[3][1] = __builtin_amdgcn_mfma_f32_16x16x32_bf16(af3, bf1, acc[3][1], 0, 0, 0);
        acc[3][2] = __builtin_amdgcn_mfma_f32_16x16x32_bf16(af3, bf2, acc[3][2], 0, 0, 0);
        acc[3][3] = __builtin_amdgcn_mfma_f32_16x16x32_bf16(af3, bf3, acc[3][3], 0, 0, 0);
        __syncthreads();
        cur ^= 1;
    }

    // epilogue: softcap+exp, reduce over vocab rows, atomics per token
    float s0 = 0.f, s1 = 0.f, s2 = 0.f, s3 = 0.f;
    #pragma unroll
    for (int mi = 0; mi < 4; ++mi) {
        #pragma unroll
        for (int r = 0; r < 4; ++r) {
            float l0 = acc[mi][0][r], l1 = acc[mi][1][r];
            float l2 = acc[mi][2][r], l3 = acc[mi][3][r];
            s0 += exp2f(CAP_C2 * __builtin_amdgcn_rcpf(exp2f(l0 * CAP_C1) + 1.0f));
            s1 += exp2f(CAP_C2 * __builtin_amdgcn_rcpf(exp2f(l1 * CAP_C1) + 1.0f));
            s2 += exp2f(CAP_C2 * __builtin_amdgcn_rcpf(exp2f(l2 * CAP_C1) + 1.0f));
            s3 += exp2f(CAP_C2 * __builtin_amdgcn_rcpf(exp2f(l3 * CAP_C1) + 1.0f));
        }
    }
    s0 += __shfl_xor(s0, 16, 64); s0 += __shfl_xor(s0, 32, 64);
    s1 += __shfl_xor(s1, 16, 64); s1 += __shfl_xor(s1, 32, 64);
    s2 += __shfl_xor(s2, 16, 64); s2 += __shfl_xor(s2, 32, 64);
    s3 += __shfl_xor(s3, 16, 64); s3 += __shfl_xor(s3, 32, 64);
    if (lane < 16) {
        int tbase = tt * 128 + wc * 64 + lane;
        atomicAdd(&rowsum[tbase +  0], s0);
        atomicAdd(&rowsum[tbase + 16], s1);
        atomicAdd(&rowsum[tbase + 32], s2);
        atomicAdd(&rowsum[tbase + 48], s3);
    }
}

// ---------------- fallback GEMM (round-3, W f32 reg-staged) — used if ws too small ----------------
__global__ __launch_bounds__(256, 3) void gemm_sumexp_fb(const float* __restrict__ W,
                                                         const short8* __restrict__ xf,
                                                         float* __restrict__ rowsum) {
    __shared__ short8 As[2][512];
    __shared__ short8 Bs[2][512];
    int bid = blockIdx.x;
    int wk  = (bid & 7) * (16000 / 8) + (bid >> 3);
    int vt  = wk >> 4;
    int tt  = wk & 15;
    const int tid  = threadIdx.x;
    const int lane = tid & 63;
    const int wid  = tid >> 6;
    const int wr   = (wid >> 1) & 1;
    const int wc   = wid & 1;
    const int mt_s = tid >> 5;
    const int sl   = tid & 31;
    const float* arow_p = W + (size_t)(vt * 128 + mt_s * 16 + (sl & 15)) * K_DIM + ((sl >> 4) << 3);
    const int nt0 = wid << 1;
    const char* gb_base = (const char*)xf + ((((size_t)(tt * 8 + nt0)) * KT_N) * 64 + lane) * 16;
    {
        const float4* gaq = (const float4*)(arow_p + 0);
        float4 p0 = gaq[0], p1 = gaq[1], p2 = gaq[4], p3 = gaq[5];
        gload16(gb_base,         &Bs[0][nt0 * 64]);
        gload16(gb_base + 32768, &Bs[0][(nt0 + 1) * 64]);
        As[0][mt_s * 64 + sl]      = pack8(p0, p1);
        As[0][mt_s * 64 + sl + 32] = pack8(p2, p3);
    }
    __syncthreads();
    f32x4 acc[4][4] = {};
    int cur = 0;
    for (int t = 0; t < NKSTEP; ++t) {
        float4 q0, q1, q2, q3;
        if (t + 1 < NKSTEP) {
            const float4* gaq = (const float4*)(arow_p + (t + 1) * 32);
            q0 = gaq[0]; q1 = gaq[1]; q2 = gaq[4]; q3 = gaq[5];
            gload16(gb_base + (size_t)(t + 1) * 1024,         &Bs[cur ^ 1][nt0 * 64]);
            gload16(gb_base + (size_t)(t + 1) * 1024 + 32768, &Bs[cur ^ 1][(nt0 + 1) * 64]);
        }
        short8 af0 = As[cur][(wr * 4 + 0) * 64 + lane];
        short8 af1 = As[cur][(wr * 4 + 1) * 64 + lane];
        short8 af2 = As[cur][(wr * 4 + 2) * 64 + lane];
        short8 af3 = As[cur][(wr * 4 + 3) * 64 + lane];
        short8 bf0 = Bs[cur][(wc * 4 + 0) * 64 + lane];
        short8 bf1 = Bs[cur][(wc * 4 + 1) * 64 + lane];
        short8 bf2 = Bs[cur][(wc * 4 + 2) * 64 + lane];
        short8 bf3 = Bs[cur][(wc * 4 + 3) * 64 + lane];
        acc[0][0] = __builtin_amdgcn_mfma_f32_16x16x32_bf16(af0, bf0, acc[0][0], 0, 0, 0);
        acc[0][1] = __builtin_amdgcn_mfma_f32_16x16x32_bf16(af0, bf1, acc[0][1], 0, 0, 0);
        acc[0][2] = __builtin_amdgcn_mfma_f32_16x16x32_bf16(af0, bf2, acc[0][2], 0, 0, 0);
        acc[0][3] = __builtin_amdgcn_mfma_f32_16x16x32_bf16(af0, bf3, acc[0][3], 0, 0, 0);
        acc[1][0] = __builtin_amdgcn_mfma_f32_16x16x32_bf16(af1, bf0, acc[1][0], 0, 0, 0);
        acc[1][1] = __builtin_amdgcn_mfma_f32_16x16x32_bf16(af1, bf1, acc[1][1], 0, 0, 0);
        acc[1][2] = __builtin_amdgcn_mfma_f32_16x16x32_bf16(af1, bf2, acc[1][2], 0, 0, 0);
        acc[1][3] = __builtin_amdgcn_mfma_f32_16x16x32_bf16(af1, bf3, acc[1][3], 0, 0, 0);
        acc[2][0] = __builtin_amdgcn_mfma_f32_16x16x32_bf16(af2, bf0, acc[2][0], 0, 0, 0);
        acc[2][1] = __builtin_amdgcn_mfma_f32_16x16x32_bf16(af2, bf1, acc[2][1], 0, 0, 0);
        acc[2][2] = __builtin_amdgcn_mfma_f32_16x16x32_bf16(af2, bf2, acc[2][2], 0, 0, 0);
        acc[2][3] = __builtin_amdgcn_mfma_f32_16x16x32_bf16(af2, bf3, acc[2][3], 0, 0, 0);
        acc[3][0] = __builtin_amdgcn_mfma_f32_16x16x32_bf16(af3, bf0, acc[3][0], 0, 0, 0);
        acc[3][1] = __builtin_amdgcn_mfma_f32_16x16x32_bf16(af3, bf1, acc[3][1], 0, 0, 0);
        acc[3][2] = __builtin_amdgcn_mfma_f32_16x16x32_bf16(af3, bf2, acc[3][2], 0, 0, 0);
        acc[3][3] = __builtin_amdgcn_mfma_f32_16x16x32_bf16(af3, bf3, acc[3][3], 0, 0, 0);
        if (t + 1 < NKSTEP) {
            As[cur ^ 1][mt_s * 64 + sl]      = pack8(q0, q1);
            As[cur ^ 1][mt_s * 64 + sl + 32] = pack8(q2, q3);
        }
        __syncthreads();
        cur ^= 1;
    }
    float s0 = 0.f, s1 = 0.f, s2 = 0.f, s3 = 0.f;
    #pragma unroll
    for (int mi = 0; mi < 4; ++mi) {
        #pragma unroll
        for (int r = 0; r < 4; ++r) {
            float l0 = acc[mi][0][r], l1 = acc[mi][1][r];
            float l2 = acc[mi][2][r], l3 = acc[mi][3][r];
            s0 += exp2f(CAP_C2 * __builtin_amdgcn_rcpf(exp2f(l0 * CAP_C1) + 1.0f));
            s1 += exp2f(CAP_C2 * __builtin_amdgcn_rcpf(exp2f(l1 * CAP_C1) + 1.0f));
            s2 += exp2f(CAP_C2 * __builtin_amdgcn_rcpf(exp2f(l2 * CAP_C1) + 1.0f));
            s3 += exp2f(CAP_C2 * __builtin_amdgcn_rcpf(exp2f(l3 * CAP_C1) + 1.0f));
        }
    }
    s0 += __shfl_xor(s0, 16, 64); s0 += __shfl_xor(s0, 32, 64);
    s1 += __shfl_xor(s1, 16, 64); s1 += __shfl_xor(s1, 32, 64);
    s2 += __shfl_xor(s2, 16, 64); s2 += __shfl_xor(s2, 32, 64);
    s3 += __shfl_xor(s3, 16, 64); s3 += __shfl_xor(s3, 32, 64);
    if (lane < 16) {
        int tbase = tt * 128 + wc * 64 + lane;
        atomicAdd(&rowsum[tbase +  0], s0);
        atomicAdd(&rowsum[tbase + 16], s1);
        atomicAdd(&rowsum[tbase + 32], s2);
        atomicAdd(&rowsum[tbase + 48], s3);
    }
}

// ---------------- exact-f32 label logits: one wave per token ----------------
__global__ __launch_bounds__(256) void label_kernel(const float* __restrict__ x,
                                                    const float* __restrict__ W,
                                                    const int* __restrict__ target,
                                                    float* __restrict__ slabel) {
    int t    = blockIdx.x * 4 + (threadIdx.x >> 6);
    int lane = threadIdx.x & 63;
    int tg   = target[t];
    int lbl  = (tg == -100) ? 0 : tg;
    const float4* xr = (const float4*)(x + (size_t)t * K_DIM);
    const float4* wv = (const float4*)(W + (size_t)lbl * K_DIM);
    float sum = 0.0f;
    #pragma unroll
    for (int i = 0; i < 4; ++i) {
        float4 a = xr[lane + i * 64];
        float4 b = wv[lane + i * 64];
        sum += a.x * b.x + a.y * b.y + a.z * b.z + a.w * b.w;
    }
    #pragma unroll
    for (int off = 1; off < 64; off <<= 1) sum += __shfl_xor(sum, off, 64);
    if (lane == 0) {
        float t0 = exp2f(sum * CAP_C1);
        slabel[t] = 30.0f - 60.0f / (t0 + 1.0f);   // 30*tanh(sum/30)
    }
}

// ---------------- finalize ----------------
__global__ __launch_bounds__(256) void finalize_kernel(const float* __restrict__ rowsum,
                                                       const float* __restrict__ slabel,
                                                       const int* __restrict__ target,
                                                       float* __restrict__ out) {
    __shared__ double ssum[4];
    __shared__ int    scnt[4];
    int w    = threadIdx.x >> 6;
    int lane = threadIdx.x & 63;
    double acc = 0.0;
    int cnt = 0;
    #pragma unroll
    for (int j = 0; j < 8; ++j) {
        int t = w * 512 + j * 64 + lane;
        int tg = target[t];
        if (tg != -100) {
            float lse = 30.0f + logf(rowsum[t]);
            acc += (double)(slabel[t] - lse);
            cnt += 1;
        }
    }
    #pragma unroll
    for (int off = 1; off < 64; off <<= 1) {
        acc += __shfl_xor(acc, off, 64);
        cnt += __shfl_xor(cnt, off, 64);
    }
    if (lane == 0) { ssum[w] = acc; scnt[w] = cnt; }
    __syncthreads();
    if (threadIdx.x == 0) {
        double c0 = ssum[0] / (double)scnt[0];
        double c1 = ssum[1] / (double)scnt[1];
        double r0 = ssum[2] / (double)scnt[2];
        double r1 = ssum[3] / (double)scnt[3];
        out[0] = (float)(-0.1 * 0.5 * ((c0 - r0) + (c1 - r1)));
    }
}

extern "C" void kernel_launch(void* const* d_in, const int* in_sizes, int n_in,
                              void* d_out, int out_size, void* d_ws, size_t ws_size,
                              hipStream_t stream) {
    const float* x      = (const float*)d_in[0];
    const float* W      = (const float*)d_in[1];
    const int*   target = (const int*)d_in[2];
    float*       out    = (float*)d_out;

    char*   ws     = (char*)d_ws;
    float*  rowsum = (float*)(ws + WS_ROWSUM);
    float*  slabel = (float*)(ws + WS_SLABEL);
    short8* xf     = (short8*)(ws + WS_XF);

    hipMemsetAsync(rowsum, 0, M_TOK * sizeof(float), stream);
    convert_x_kernel<<<M_TOK * (K_DIM / 8) / 256, 256, 0, stream>>>(x, xf);

    if (ws_size >= WS_REQ) {
        short8* wf = (short8*)(ws + WS_WF);
        convert_w_kernel<<<V_DIM * (K_DIM / 8) / 256, 256, 0, stream>>>(W, wf);
        gemm_sumexp_bf16<<<(V_DIM / 128) * 16, 256, 0, stream>>>(wf, xf, rowsum);
    } else {
        gemm_sumexp_fb<<<(V_DIM / 128) * 16, 256, 0, stream>>>(W, xf, rowsum);
    }

    label_kernel<<<M_TOK / 4, 256, 0, stream>>>(x, W, target, slabel);
    finalize_kernel<<<1, 256, 0, stream>>>(rowsum, slabel, target, out);
}

// Round 5
// 448.664 us; speedup vs baseline: 7.5543x; 1.6183x over previous
//
#include <hip/hip_runtime.h>
#include <hip/hip_bf16.h>

typedef __attribute__((ext_vector_type(8)))  short short8;   // 8 bf16
typedef __attribute__((ext_vector_type(8)))  int   int8v;    // 32 fp8
typedef __attribute__((ext_vector_type(4)))  float f32x4;
typedef __attribute__((ext_vector_type(16))) float f32x16;

#define K_DIM 1024
#define KT_N  32
#define M_TOK 2048
#define V_DIM 128000

// softcap s = 30*tanh(l/30);  exp(s-30) = exp2(C2/(t+1)) with t = exp2(l*C1)
#define CAP_C1 0.09617966939259757f
#define CAP_C2 -86.56170245333781f
// fp8 path: W pre-scaled by 32 -> raw logit = 32*l_true; fold into C1
#define CAP_C1S (0.09617966939259757f / 32.0f)

// workspace layout (bytes)
#define WS_ROWSUM 0
#define WS_SLABEL 8192
#define WS_XQ     16384
#define WS_XFB    (16384 + (2u << 20))
#define WS_WQ     (16384 + (2u << 20) + (4u << 20))
#define WS_REQ    ((size_t)WS_WQ + (size_t)V_DIM * K_DIM)

static __device__ __forceinline__ short f2bf(float f) {
    unsigned u = __float_as_uint(f);
    u += 0x7FFFu + ((u >> 16) & 1u);
    return (short)(u >> 16);
}
static __device__ __forceinline__ short8 pack8(float4 a, float4 b) {
    short8 r;
    r[0] = f2bf(a.x); r[1] = f2bf(a.y); r[2] = f2bf(a.z); r[3] = f2bf(a.w);
    r[4] = f2bf(b.x); r[5] = f2bf(b.y); r[6] = f2bf(b.z); r[7] = f2bf(b.w);
    return r;
}
static __device__ __forceinline__ void gload16(const void* g, void* lds) {
    __builtin_amdgcn_global_load_lds(
        (const __attribute__((address_space(1))) unsigned int*)g,
        (__attribute__((address_space(3))) unsigned int*)lds, 16, 0, 0);
}
static __device__ __forceinline__ int cvt4(float4 f, float mul) {
    int w = 0;
    w = __builtin_amdgcn_cvt_pk_fp8_f32(f.x * mul, f.y * mul, w, false);
    w = __builtin_amdgcn_cvt_pk_fp8_f32(f.z * mul, f.w * mul, w, true);
    return w;
}

// ---------------- f32 row-major -> fp8 e4m3 MFMA fragment stream ----------------
// stream int4 index: ((mtg32*16 + t)*2 + h)*64 + lane
// lane l of frag mtg32 holds row = mtg32*32 + (l&31), k = t*64 + (l>>5)*32 + h*16 + 0..15
__global__ __launch_bounds__(256) void convert_fp8_kernel(const float* __restrict__ src,
                                                          int4* __restrict__ dst, float mul) {
    int o  = blockIdx.x * 256 + threadIdx.x;
    int l  = o & 63;
    int ft = o >> 6;                      // mtg32*16 + t
    int row = (ft >> 4) * 32 + (l & 31);
    int k   = ((ft & 15) << 6) + ((l >> 5) << 5);
    const float4* s = (const float4*)(src + (size_t)row * K_DIM + k);
    float4 f0 = s[0], f1 = s[1], f2 = s[2], f3 = s[3];
    float4 f4 = s[4], f5 = s[5], f6 = s[6], f7 = s[7];
    dst[((size_t)ft * 2 + 0) * 64 + l] =
        make_int4(cvt4(f0, mul), cvt4(f1, mul), cvt4(f2, mul), cvt4(f3, mul));
    dst[((size_t)ft * 2 + 1) * 64 + l] =
        make_int4(cvt4(f4, mul), cvt4(f5, mul), cvt4(f6, mul), cvt4(f7, mul));
}

// ---------------- bf16 converter (fallback path only) ----------------
__global__ __launch_bounds__(256) void convert_x_kernel(const float* __restrict__ x,
                                                        short8* __restrict__ xf) {
    int o = blockIdx.x * 256 + threadIdx.x;
    int lane = o & 63;
    int frag = o >> 6;
    int kt = frag & (KT_N - 1);
    int mt = frag >> 5;
    int row = (mt << 4) | (lane & 15);
    int k   = (kt << 5) | ((lane >> 4) << 3);
    const float4* s = (const float4*)(x + (size_t)row * K_DIM + k);
    xf[o] = pack8(s[0], s[1]);
}

static __device__ __forceinline__ int8v ld_frag(const int4* buf, int f, int lane) {
    int4 lo = buf[(f * 2 + 0) * 64 + lane];
    int4 hi = buf[(f * 2 + 1) * 64 + lane];
    int8v r;
    r[0] = lo.x; r[1] = lo.y; r[2] = lo.z; r[3] = lo.w;
    r[4] = hi.x; r[5] = hi.y; r[6] = hi.z; r[7] = hi.w;
    return r;
}
static __device__ __forceinline__ float expterm(float lraw) {
    return exp2f(CAP_C2 * __builtin_amdgcn_rcpf(exp2f(lraw * CAP_C1S) + 1.0f));
}

// ---------------- MX-fp8 GEMM + softcap-exp + vocab-reduce ----------------
// Tile 128 vocab x 128 tok, BK=64 (mfma_scale 32x32x64), 16 K-steps, 4 waves 2x2,
// wave tile 64x64 = 2x2 frags of 32x32, dbuf LDS 32 KiB, 1 barrier/K-step.
__global__ __launch_bounds__(256, 3) void gemm_sumexp_fp8(const int4* __restrict__ wq,
                                                          const int4* __restrict__ xq,
                                                          float* __restrict__ rowsum) {
    __shared__ int4 As[2][512];          // 4 frags x 2 halves x 64 lanes, 8 KiB/buf
    __shared__ int4 Bs[2][512];

    int bid = blockIdx.x;
    int wk  = (bid & 7) * 2000 + (bid >> 3);   // XCD swizzle, 16000 % 8 == 0
    int vt  = wk >> 4;                   // vocab tile 0..999
    int tt  = wk & 15;                   // token tile 0..15

    const int tid  = threadIdx.x;
    const int lane = tid & 63;
    const int wid  = tid >> 6;
    const int wr   = (wid >> 1) & 1;     // wave row (vocab frags wr*2..+1)
    const int wc   = wid & 1;            // wave col (token frags wc*2..+1)

    // staging: waves 0,1 -> A frags {0,1},{2,3}; waves 2,3 -> B frags {0,1},{2,3}
    const bool isA = (wid < 2);
    const int  f0  = (wid & 1) * 2;
    const int4* gbase = isA ? (wq + ((size_t)(vt * 4 + f0)) * 2048 + lane)
                            : (xq + ((size_t)(tt * 4 + f0)) * 2048 + lane);

    // prologue: stage K-step 0 into buf 0
    {
        int4* db = isA ? &As[0][0] : &Bs[0][0];
        gload16(gbase,               &db[(f0 * 2 + 0) * 64]);
        gload16(gbase + 64,          &db[(f0 * 2 + 1) * 64]);
        gload16(gbase + 2048,        &db[((f0 + 1) * 2 + 0) * 64]);
        gload16(gbase + 2048 + 64,   &db[((f0 + 1) * 2 + 1) * 64]);
    }
    __syncthreads();

    f32x16 acc[2][2] = {};
    int cur = 0;
    for (int t = 0; t < 16; ++t) {
        if (t + 1 < 16) {
            int4* db = isA ? &As[cur ^ 1][0] : &Bs[cur ^ 1][0];
            const int4* g = gbase + (size_t)(t + 1) * 128;
            gload16(g,             &db[(f0 * 2 + 0) * 64]);
            gload16(g + 64,        &db[(f0 * 2 + 1) * 64]);
            gload16(g + 2048,      &db[((f0 + 1) * 2 + 0) * 64]);
            gload16(g + 2048 + 64, &db[((f0 + 1) * 2 + 1) * 64]);
        }
        int8v a0 = ld_frag(&As[cur][0], wr * 2 + 0, lane);
        int8v a1 = ld_frag(&As[cur][0], wr * 2 + 1, lane);
        int8v b0 = ld_frag(&Bs[cur][0], wc * 2 + 0, lane);
        int8v b1 = ld_frag(&Bs[cur][0], wc * 2 + 1, lane);
        acc[0][0] = __builtin_amdgcn_mfma_scale_f32_32x32x64_f8f6f4(
            a0, b0, acc[0][0], 0, 0, 0, 0x7F7F7F7F, 0, 0x7F7F7F7F);
        acc[0][1] = __builtin_amdgcn_mfma_scale_f32_32x32x64_f8f6f4(
            a0, b1, acc[0][1], 0, 0, 0, 0x7F7F7F7F, 0, 0x7F7F7F7F);
        acc[1][0] = __builtin_amdgcn_mfma_scale_f32_32x32x64_f8f6f4(
            a1, b0, acc[1][0], 0, 0, 0, 0x7F7F7F7F, 0, 0x7F7F7F7F);
        acc[1][1] = __builtin_amdgcn_mfma_scale_f32_32x32x64_f8f6f4(
            a1, b1, acc[1][1], 0, 0, 0, 0x7F7F7F7F, 0, 0x7F7F7F7F);
        __syncthreads();
        cur ^= 1;
    }

    // epilogue: softcap+exp, reduce over vocab rows, atomics per token
    #pragma unroll
    for (int j = 0; j < 2; ++j) {
        float e = 0.f;
        #pragma unroll
        for (int i = 0; i < 2; ++i) {
            #pragma unroll
            for (int r = 0; r < 16; ++r) e += expterm(acc[i][j][r]);
        }
        e += __shfl_xor(e, 32, 64);      // merge the two 16-row halves
        if (lane < 32) {
            atomicAdd(&rowsum[tt * 128 + wc * 64 + j * 32 + lane], e);
        }
    }
}

// ---------------- fallback GEMM (bf16, W f32 reg-staged) — used if ws too small ----------------
__global__ __launch_bounds__(256, 3) void gemm_sumexp_fb(const float* __restrict__ W,
                                                         const short8* __restrict__ xf,
                                                         float* __restrict__ rowsum) {
    __shared__ short8 As[2][512];
    __shared__ short8 Bs[2][512];
    int bid = blockIdx.x;
    int wk  = (bid & 7) * 2000 + (bid >> 3);
    int vt  = wk >> 4;
    int tt  = wk & 15;
    const int tid  = threadIdx.x;
    const int lane = tid & 63;
    const int wid  = tid >> 6;
    const int wr   = (wid >> 1) & 1;
    const int wc   = wid & 1;
    const int mt_s = tid >> 5;
    const int sl   = tid & 31;
    const float* arow_p = W + (size_t)(vt * 128 + mt_s * 16 + (sl & 15)) * K_DIM + ((sl >> 4) << 3);
    const int nt0 = wid << 1;
    const char* gb_base = (const char*)xf + ((((size_t)(tt * 8 + nt0)) * KT_N) * 64 + lane) * 16;
    {
        const float4* gaq = (const float4*)(arow_p + 0);
        float4 p0 = gaq[0], p1 = gaq[1], p2 = gaq[4], p3 = gaq[5];
        gload16(gb_base,         &Bs[0][nt0 * 64]);
        gload16(gb_base + 32768, &Bs[0][(nt0 + 1) * 64]);
        As[0][mt_s * 64 + sl]      = pack8(p0, p1);
        As[0][mt_s * 64 + sl + 32] = pack8(p2, p3);
    }
    __syncthreads();
    f32x4 acc[4][4] = {};
    int cur = 0;
    for (int t = 0; t < 32; ++t) {
        float4 q0, q1, q2, q3;
        if (t + 1 < 32) {
            const float4* gaq = (const float4*)(arow_p + (t + 1) * 32);
            q0 = gaq[0]; q1 = gaq[1]; q2 = gaq[4]; q3 = gaq[5];
            gload16(gb_base + (size_t)(t + 1) * 1024,         &Bs[cur ^ 1][nt0 * 64]);
            gload16(gb_base + (size_t)(t + 1) * 1024 + 32768, &Bs[cur ^ 1][(nt0 + 1) * 64]);
        }
        short8 af0 = As[cur][(wr * 4 + 0) * 64 + lane];
        short8 af1 = As[cur][(wr * 4 + 1) * 64 + lane];
        short8 af2 = As[cur][(wr * 4 + 2) * 64 + lane];
        short8 af3 = As[cur][(wr * 4 + 3) * 64 + lane];
        short8 bf0 = Bs[cur][(wc * 4 + 0) * 64 + lane];
        short8 bf1 = Bs[cur][(wc * 4 + 1) * 64 + lane];
        short8 bf2 = Bs[cur][(wc * 4 + 2) * 64 + lane];
        short8 bf3 = Bs[cur][(wc * 4 + 3) * 64 + lane];
        acc[0][0] = __builtin_amdgcn_mfma_f32_16x16x32_bf16(af0, bf0, acc[0][0], 0, 0, 0);
        acc[0][1] = __builtin_amdgcn_mfma_f32_16x16x32_bf16(af0, bf1, acc[0][1], 0, 0, 0);
        acc[0][2] = __builtin_amdgcn_mfma_f32_16x16x32_bf16(af0, bf2, acc[0][2], 0, 0, 0);
        acc[0][3] = __builtin_amdgcn_mfma_f32_16x16x32_bf16(af0, bf3, acc[0][3], 0, 0, 0);
        acc[1][0] = __builtin_amdgcn_mfma_f32_16x16x32_bf16(af1, bf0, acc[1][0], 0, 0, 0);
        acc[1][1] = __builtin_amdgcn_mfma_f32_16x16x32_bf16(af1, bf1, acc[1][1], 0, 0, 0);
        acc[1][2] = __builtin_amdgcn_mfma_f32_16x16x32_bf16(af1, bf2, acc[1][2], 0, 0, 0);
        acc[1][3] = __builtin_amdgcn_mfma_f32_16x16x32_bf16(af1, bf3, acc[1][3], 0, 0, 0);
        acc[2][0] = __builtin_amdgcn_mfma_f32_16x16x32_bf16(af2, bf0, acc[2][0], 0, 0, 0);
        acc[2][1] = __builtin_amdgcn_mfma_f32_16x16x32_bf16(af2, bf1, acc[2][1], 0, 0, 0);
        acc[2][2] = __builtin_amdgcn_mfma_f32_16x16x32_bf16(af2, bf2, acc[2][2], 0, 0, 0);
        acc[2][3] = __builtin_amdgcn_mfma_f32_16x16x32_bf16(af2, bf3, acc[2][3], 0, 0, 0);
        acc[3][0] = __builtin_amdgcn_mfma_f32_16x16x32_bf16(af3, bf0, acc[3][0], 0, 0, 0);
        acc[3][1] = __builtin_amdgcn_mfma_f32_16x16x32_bf16(af3, bf1, acc[3][1], 0, 0, 0);
        acc[3][2] = __builtin_amdgcn_mfma_f32_16x16x32_bf16(af3, bf2, acc[3][2], 0, 0, 0);
        acc[3][3] = __builtin_amdgcn_mfma_f32_16x16x32_bf16(af3, bf3, acc[3][3], 0, 0, 0);
        if (t + 1 < 32) {
            As[cur ^ 1][mt_s * 64 + sl]      = pack8(q0, q1);
            As[cur ^ 1][mt_s * 64 + sl + 32] = pack8(q2, q3);
        }
        __syncthreads();
        cur ^= 1;
    }
    float s0 = 0.f, s1 = 0.f, s2 = 0.f, s3 = 0.f;
    #pragma unroll
    for (int mi = 0; mi < 4; ++mi) {
        #pragma unroll
        for (int r = 0; r < 4; ++r) {
            float l0 = acc[mi][0][r], l1 = acc[mi][1][r];
            float l2 = acc[mi][2][r], l3 = acc[mi][3][r];
            s0 += exp2f(CAP_C2 * __builtin_amdgcn_rcpf(exp2f(l0 * CAP_C1) + 1.0f));
            s1 += exp2f(CAP_C2 * __builtin_amdgcn_rcpf(exp2f(l1 * CAP_C1) + 1.0f));
            s2 += exp2f(CAP_C2 * __builtin_amdgcn_rcpf(exp2f(l2 * CAP_C1) + 1.0f));
            s3 += exp2f(CAP_C2 * __builtin_amdgcn_rcpf(exp2f(l3 * CAP_C1) + 1.0f));
        }
    }
    s0 += __shfl_xor(s0, 16, 64); s0 += __shfl_xor(s0, 32, 64);
    s1 += __shfl_xor(s1, 16, 64); s1 += __shfl_xor(s1, 32, 64);
    s2 += __shfl_xor(s2, 16, 64); s2 += __shfl_xor(s2, 32, 64);
    s3 += __shfl_xor(s3, 16, 64); s3 += __shfl_xor(s3, 32, 64);
    if (lane < 16) {
        int tbase = tt * 128 + wc * 64 + lane;
        atomicAdd(&rowsum[tbase +  0], s0);
        atomicAdd(&rowsum[tbase + 16], s1);
        atomicAdd(&rowsum[tbase + 32], s2);
        atomicAdd(&rowsum[tbase + 48], s3);
    }
}

// ---------------- exact-f32 label logits ----------------
__global__ __launch_bounds__(256) void label_kernel(const float* __restrict__ x,
                                                    const float* __restrict__ W,
                                                    const int* __restrict__ target,
                                                    float* __restrict__ slabel) {
    int t    = blockIdx.x * 4 + (threadIdx.x >> 6);
    int lane = threadIdx.x & 63;
    int tg   = target[t];
    int lbl  = (tg == -100) ? 0 : tg;
    const float4* xr = (const float4*)(x + (size_t)t * K_DIM);
    const float4* wv = (const float4*)(W + (size_t)lbl * K_DIM);
    float sum = 0.0f;
    #pragma unroll
    for (int i = 0; i < 4; ++i) {
        float4 a = xr[lane + i * 64];
        float4 b = wv[lane + i * 64];
        sum += a.x * b.x + a.y * b.y + a.z * b.z + a.w * b.w;
    }
    #pragma unroll
    for (int off = 1; off < 64; off <<= 1) sum += __shfl_xor(sum, off, 64);
    if (lane == 0) {
        float t0 = exp2f(sum * CAP_C1);
        slabel[t] = 30.0f - 60.0f / (t0 + 1.0f);
    }
}

// ---------------- finalize ----------------
__global__ __launch_bounds__(256) void finalize_kernel(const float* __restrict__ rowsum,
                                                       const float* __restrict__ slabel,
                                                       const int* __restrict__ target,
                                                       float* __restrict__ out) {
    __shared__ double ssum[4];
    __shared__ int    scnt[4];
    int w    = threadIdx.x >> 6;
    int lane = threadIdx.x & 63;
    double acc = 0.0;
    int cnt = 0;
    #pragma unroll
    for (int j = 0; j < 8; ++j) {
        int t = w * 512 + j * 64 + lane;
        int tg = target[t];
        if (tg != -100) {
            float lse = 30.0f + logf(rowsum[t]);
            acc += (double)(slabel[t] - lse);
            cnt += 1;
        }
    }
    #pragma unroll
    for (int off = 1; off < 64; off <<= 1) {
        acc += __shfl_xor(acc, off, 64);
        cnt += __shfl_xor(cnt, off, 64);
    }
    if (lane == 0) { ssum[w] = acc; scnt[w] = cnt; }
    __syncthreads();
    if (threadIdx.x == 0) {
        double c0 = ssum[0] / (double)scnt[0];
        double c1 = ssum[1] / (double)scnt[1];
        double r0 = ssum[2] / (double)scnt[2];
        double r1 = ssum[3] / (double)scnt[3];
        out[0] = (float)(-0.1 * 0.5 * ((c0 - r0) + (c1 - r1)));
    }
}

extern "C" void kernel_launch(void* const* d_in, const int* in_sizes, int n_in,
                              void* d_out, int out_size, void* d_ws, size_t ws_size,
                              hipStream_t stream) {
    const float* x      = (const float*)d_in[0];
    const float* W      = (const float*)d_in[1];
    const int*   target = (const int*)d_in[2];
    float*       out    = (float*)d_out;

    char*   ws     = (char*)d_ws;
    float*  rowsum = (float*)(ws + WS_ROWSUM);
    float*  slabel = (float*)(ws + WS_SLABEL);

    hipMemsetAsync(rowsum, 0, M_TOK * sizeof(float), stream);

    if (ws_size >= WS_REQ) {
        int4* xq = (int4*)(ws + WS_XQ);
        int4* wq = (int4*)(ws + WS_WQ);
        // x: 64 frags of 32 rows * 16 ksteps * 64 lanes = 65536 threads
        convert_fp8_kernel<<<256, 256, 0, stream>>>(x, xq, 1.0f);
        // W: 4000 frags * 16 * 64 = 4.096M threads
        convert_fp8_kernel<<<16000, 256, 0, stream>>>(W, wq, 32.0f);
        gemm_sumexp_fp8<<<16000, 256, 0, stream>>>(wq, xq, rowsum);
    } else {
        short8* xf = (short8*)(ws + WS_XFB);
        convert_x_kernel<<<M_TOK * (K_DIM / 8) / 256, 256, 0, stream>>>(x, xf);
        gemm_sumexp_fb<<<16000, 256, 0, stream>>>(W, xf, rowsum);
    }

    label_kernel<<<M_TOK / 4, 256, 0, stream>>>(x, W, target, slabel);
    finalize_kernel<<<1, 256, 0, stream>>>(rowsum, slabel, target, out);
}